// Round 2
// baseline (569.378 us; speedup 1.0000x reference)
//
#include <hip/hip_runtime.h>
#include <hip/hip_bf16.h>

#define N_NODES 100000
#define N_EDGES 3200000
#define F_IN    512
#define F_H     16
#define F_OUT   7
#define SCAN_G  ((N_NODES + 255) / 256)   // 391

// ---------------- degree count ----------------
__global__ __launch_bounds__(256) void k_count(const int* __restrict__ ei,
                                               int* __restrict__ deg) {
  int stride = gridDim.x * blockDim.x;
  for (int e = blockIdx.x * blockDim.x + threadIdx.x; e < N_EDGES; e += stride) {
    atomicAdd(&deg[ei[N_EDGES + e]], 1);   // dst half
  }
}

// ---------------- dinv = rsqrt(deg + 1 self-loop) ----------------
__global__ __launch_bounds__(256) void k_dinv(const int* __restrict__ deg,
                                              float* __restrict__ dinv) {
  int i = blockIdx.x * blockDim.x + threadIdx.x;
  if (i < N_NODES) dinv[i] = rsqrtf((float)(deg[i] + 1));
}

// ---------------- 3-kernel exclusive scan of deg -> rowptr ----------------
__global__ __launch_bounds__(256) void k_scanA(const int* __restrict__ deg,
                                               int* __restrict__ rowptr,
                                               int* __restrict__ bsums) {
  __shared__ int lds[256];
  int tid = threadIdx.x;
  int i = blockIdx.x * 256 + tid;
  int c = (i < N_NODES) ? deg[i] : 0;
  lds[tid] = c;
  __syncthreads();
  for (int off = 1; off < 256; off <<= 1) {
    int v = (tid >= off) ? lds[tid - off] : 0;
    __syncthreads();
    lds[tid] += v;
    __syncthreads();
  }
  if (i < N_NODES) rowptr[i] = lds[tid] - c;       // exclusive
  if (tid == 255) bsums[blockIdx.x] = lds[tid];    // block total
}

__global__ __launch_bounds__(512) void k_scanB(int* __restrict__ bsums, int G) {
  __shared__ int lds[512];
  int tid = threadIdx.x;
  int c = (tid < G) ? bsums[tid] : 0;
  lds[tid] = c;
  __syncthreads();
  for (int off = 1; off < 512; off <<= 1) {
    int v = (tid >= off) ? lds[tid - off] : 0;
    __syncthreads();
    lds[tid] += v;
    __syncthreads();
  }
  if (tid < G) bsums[tid] = lds[tid] - c;          // exclusive block offsets
}

__global__ __launch_bounds__(256) void k_scanC(int* __restrict__ rowptr,
                                               const int* __restrict__ bsums) {
  int i = blockIdx.x * blockDim.x + threadIdx.x;
  if (i < N_NODES) rowptr[i] += bsums[blockIdx.x];
}

// ---------------- scatter edges into CSR ----------------
__global__ __launch_bounds__(256) void k_scatter(const int* __restrict__ ei,
                                                 const int* __restrict__ rowptr,
                                                 int* __restrict__ cursor,
                                                 int* __restrict__ colsrc) {
  int stride = gridDim.x * blockDim.x;
  for (int e = blockIdx.x * blockDim.x + threadIdx.x; e < N_EDGES; e += stride) {
    int s = ei[e];
    int d = ei[N_EDGES + e];
    int pos = rowptr[d] + atomicAdd(&cursor[d], 1);
    colsrc[pos] = s;
  }
}

// ---------------- GEMM1: h1 = x @ W1  [N,512]x[512,16] ----------------
// wave = 16 rows; lane: g = lane&7 (k-slice), h = lane>>3 (row pair).
// W1^T staged in LDS [16][512] so b128 reads along k are conflict-free.
__global__ __launch_bounds__(256) void k_gemm1(const float* __restrict__ x,
                                               const float* __restrict__ W1,
                                               float* __restrict__ h1) {
  __shared__ float Wt[F_H * F_IN];   // 32 KB, transposed [j][k]
  int tid = threadIdx.x;
  for (int idx = tid; idx < F_IN * F_H; idx += 256) {
    int k = idx >> 4, j = idx & 15;
    Wt[j * F_IN + k] = W1[idx];
  }
  __syncthreads();

  int wave = tid >> 6, lane = tid & 63;
  int g = lane & 7, h = lane >> 3;
  int base = (blockIdx.x * 4 + wave) * 16;
  if (base >= N_NODES) return;
  int rowA = base + h * 2, rowB = rowA + 1;

  float accA[16], accB[16];
#pragma unroll
  for (int j = 0; j < 16; j++) { accA[j] = 0.f; accB[j] = 0.f; }

  const float4* xa = (const float4*)(x + (size_t)rowA * F_IN);
  const float4* xb = (const float4*)(x + (size_t)rowB * F_IN);

  for (int t = 0; t < 16; t++) {
    int k0 = g * 4 + t * 32;
    float4 a = xa[g + t * 8];
    float4 b = xb[g + t * 8];
#pragma unroll
    for (int j = 0; j < 16; j++) {
      float4 wv = *(const float4*)(&Wt[j * F_IN + k0]);
      accA[j] += a.x * wv.x + a.y * wv.y + a.z * wv.z + a.w * wv.w;
      accB[j] += b.x * wv.x + b.y * wv.y + b.z * wv.z + b.w * wv.w;
    }
  }
  // reduce across the 8 k-slice lanes (xor 1,2,4 stays inside the group)
#pragma unroll
  for (int off = 1; off < 8; off <<= 1) {
#pragma unroll
    for (int j = 0; j < 16; j++) {
      accA[j] += __shfl_xor(accA[j], off, 64);
      accB[j] += __shfl_xor(accB[j], off, 64);
    }
  }
  if (g == 0) {
    float4* oa = (float4*)(h1 + (size_t)rowA * F_H);
    oa[0] = make_float4(accA[0], accA[1], accA[2], accA[3]);
    oa[1] = make_float4(accA[4], accA[5], accA[6], accA[7]);
    oa[2] = make_float4(accA[8], accA[9], accA[10], accA[11]);
    oa[3] = make_float4(accA[12], accA[13], accA[14], accA[15]);
    float4* ob = (float4*)(h1 + (size_t)rowB * F_H);
    ob[0] = make_float4(accB[0], accB[1], accB[2], accB[3]);
    ob[1] = make_float4(accB[4], accB[5], accB[6], accB[7]);
    ob[2] = make_float4(accB[8], accB[9], accB[10], accB[11]);
    ob[3] = make_float4(accB[12], accB[13], accB[14], accB[15]);
  }
}

// ---------------- agg layer 1: wave/node, 16 feat lanes x 4 slots ----------------
__global__ __launch_bounds__(256) void k_agg1(const float* __restrict__ h1,
                                              const int* __restrict__ colsrc,
                                              const int* __restrict__ rowptr,
                                              const int* __restrict__ deg,
                                              const float* __restrict__ dinv,
                                              const float* __restrict__ b1,
                                              float* __restrict__ h2) {
  int wid = (blockIdx.x * blockDim.x + threadIdx.x) >> 6;
  if (wid >= N_NODES) return;
  int i = wid;
  int lane = threadIdx.x & 63;
  int j = lane & 15, q = lane >> 4;
  int start = rowptr[i], cnt = deg[i];
  float acc = 0.f;
  for (int e = q; e < cnt; e += 4) {
    int src = colsrc[start + e];
    acc += dinv[src] * h1[src * F_H + j];
  }
  acc += __shfl_xor(acc, 16, 64);
  acc += __shfl_xor(acc, 32, 64);
  if (q == 0) {
    float di = dinv[i];
    float v = di * acc + di * di * h1[i * F_H + j] + b1[j];
    h2[i * F_H + j] = v > 0.f ? v : 0.f;   // ReLU fused
  }
}

// ---------------- GEMM2: g = h2 @ W2  [N,16]x[16,7] ----------------
__global__ __launch_bounds__(256) void k_gemm2(const float* __restrict__ h2,
                                               const float* __restrict__ W2,
                                               float* __restrict__ gfeat) {
  __shared__ float w[F_H * F_OUT];
  if (threadIdx.x < F_H * F_OUT) w[threadIdx.x] = W2[threadIdx.x];
  __syncthreads();
  int i = blockIdx.x * blockDim.x + threadIdx.x;
  if (i >= N_NODES) return;
  const float4* hp = (const float4*)(h2 + (size_t)i * F_H);
  float4 h0 = hp[0], h1v = hp[1], h2v = hp[2], h3v = hp[3];
  float hh[16] = {h0.x, h0.y, h0.z, h0.w, h1v.x, h1v.y, h1v.z, h1v.w,
                  h2v.x, h2v.y, h2v.z, h2v.w, h3v.x, h3v.y, h3v.z, h3v.w};
  float o[7] = {0.f, 0.f, 0.f, 0.f, 0.f, 0.f, 0.f};
#pragma unroll
  for (int k = 0; k < 16; k++)
#pragma unroll
    for (int j = 0; j < 7; j++)
      o[j] += hh[k] * w[k * 7 + j];
#pragma unroll
  for (int j = 0; j < 7; j++) gfeat[i * 7 + j] = o[j];
}

// ---------------- agg layer 2 + bias + log_softmax ----------------
__global__ __launch_bounds__(256) void k_agg2(const float* __restrict__ gfeat,
                                              const int* __restrict__ colsrc,
                                              const int* __restrict__ rowptr,
                                              const int* __restrict__ deg,
                                              const float* __restrict__ dinv,
                                              const float* __restrict__ b2,
                                              float* __restrict__ out) {
  int wid = (blockIdx.x * blockDim.x + threadIdx.x) >> 6;
  if (wid >= N_NODES) return;
  int i = wid;
  int lane = threadIdx.x & 63;
  int j = lane & 7, q = lane >> 3;
  bool act = (j < 7);
  int start = rowptr[i], cnt = deg[i];
  float acc = 0.f;
  for (int e = q; e < cnt; e += 8) {
    int src = colsrc[start + e];
    if (act) acc += dinv[src] * gfeat[src * F_OUT + j];
  }
  acc += __shfl_xor(acc, 8, 64);
  acc += __shfl_xor(acc, 16, 64);
  acc += __shfl_xor(acc, 32, 64);
  float v = -1e30f;
  if (act) {
    float di = dinv[i];
    v = di * acc + di * di * gfeat[i * F_OUT + j] + b2[j];
  }
  // log_softmax over the 7 features (lane bits 0..2)
  float m = v;
  m = fmaxf(m, __shfl_xor(m, 1, 64));
  m = fmaxf(m, __shfl_xor(m, 2, 64));
  m = fmaxf(m, __shfl_xor(m, 4, 64));
  float ex = act ? expf(v - m) : 0.f;
  float s = ex;
  s += __shfl_xor(s, 1, 64);
  s += __shfl_xor(s, 2, 64);
  s += __shfl_xor(s, 4, 64);
  if (q == 0 && act) out[i * F_OUT + j] = v - m - logf(s);
}

extern "C" void kernel_launch(void* const* d_in, const int* in_sizes, int n_in,
                              void* d_out, int out_size, void* d_ws, size_t ws_size,
                              hipStream_t stream) {
  const float* x  = (const float*)d_in[0];
  const int*   ei = (const int*)d_in[1];     // int32 per harness spec; [0..E)=src, [E..2E)=dst
  const float* W1 = (const float*)d_in[2];
  const float* b1 = (const float*)d_in[3];
  const float* W2 = (const float*)d_in[4];
  const float* b2 = (const float*)d_in[5];
  float* out = (float*)d_out;

  // workspace layout (~30 MB total)
  char* base = (char*)d_ws;
  int*   deg     = (int*)(base + 0);          //  400128
  int*   cursor  = (int*)(base + 400128);     //  400128
  float* dinv    = (float*)(base + 800256);   //  400128
  int*   rowptr  = (int*)(base + 1200384);    //  400128
  int*   bsums   = (int*)(base + 1600512);    //  2048
  int*   colsrc  = (int*)(base + 1602560);    //  12.8 MB
  float* h1      = (float*)(base + 14402560); //  6.4 MB
  float* h2      = (float*)(base + 20802560); //  6.4 MB
  float* gfeat   = (float*)(base + 27202560); //  2.8 MB  (end 30002560)

  // zero deg + cursor (adjacent)
  hipMemsetAsync(base, 0, 800256, stream);

  k_count  <<<2048, 256, 0, stream>>>(ei, deg);
  k_dinv   <<<SCAN_G, 256, 0, stream>>>(deg, dinv);
  k_scanA  <<<SCAN_G, 256, 0, stream>>>(deg, rowptr, bsums);
  k_scanB  <<<1, 512, 0, stream>>>(bsums, SCAN_G);
  k_scanC  <<<SCAN_G, 256, 0, stream>>>(rowptr, bsums);
  k_scatter<<<2048, 256, 0, stream>>>(ei, rowptr, cursor, colsrc);

  k_gemm1  <<<(N_NODES / 16 + 3) / 4, 256, 0, stream>>>(x, W1, h1);
  k_agg1   <<<N_NODES / 4, 256, 0, stream>>>(h1, colsrc, rowptr, deg, dinv, b1, h2);
  k_gemm2  <<<SCAN_G, 256, 0, stream>>>(h2, W2, gfeat);
  k_agg2   <<<N_NODES / 4, 256, 0, stream>>>(gfeat, colsrc, rowptr, deg, dinv, b2, out);
}

// Round 3
// 509.110 us; speedup vs baseline: 1.1184x; 1.1184x over previous
//
#include <hip/hip_runtime.h>
#include <hip/hip_bf16.h>

#define N_NODES 100000
#define N_EDGES 3200000
#define F_IN    512
#define F_H     16
#define F_OUT   7
#define NB      391      // buckets of 256 dst nodes: ceil(100000/256)
#define CAP     32       // LDS staging entries per bucket

typedef unsigned int u32;

// ---------------- pass 1: bucket histogram ----------------
__global__ __launch_bounds__(256) void k_bhist(const int* __restrict__ dst,
                                               int* __restrict__ bcnt) {
  __shared__ int h[NB];
  int tid = threadIdx.x;
  for (int b = tid; b < NB; b += 256) h[b] = 0;
  __syncthreads();
  int stride = gridDim.x * blockDim.x;
  for (int e = blockIdx.x * blockDim.x + tid; e < N_EDGES; e += stride)
    atomicAdd(&h[dst[e] >> 8], 1);
  __syncthreads();
  for (int b = tid; b < NB; b += 256)
    if (h[b]) atomicAdd(&bcnt[b], h[b]);
}

// ---------------- pass 2: padded exclusive scan of bucket counts ----------------
__global__ __launch_bounds__(512) void k_bscan(const int* __restrict__ bcnt,
                                               int* __restrict__ pbase,
                                               int* __restrict__ gcur) {
  __shared__ int lds[512];
  int tid = threadIdx.x;
  int c = (tid < NB) ? bcnt[tid] : 0;
  int p = (c + 31) & ~31;            // pad to CAP multiple -> aligned chunk flushes
  lds[tid] = p;
  __syncthreads();
  for (int off = 1; off < 512; off <<= 1) {
    int v = (tid >= off) ? lds[tid - off] : 0;
    __syncthreads();
    lds[tid] += v;
    __syncthreads();
  }
  if (tid < NB) {
    int ex = lds[tid] - p;
    pbase[tid] = ex;
    gcur[tid] = ex;
  }
}

// ---------------- pass 3: staged binning scatter ----------------
// pack: (dst_local << 17) | src   (dst_local < 256, src < 2^17)
__global__ __launch_bounds__(256) void k_bin(const int* __restrict__ src,
                                             const int* __restrict__ dst,
                                             int* __restrict__ gcur,
                                             u32* __restrict__ pairs) {
  __shared__ u32 stage[NB * CAP];   // ~50 KB
  __shared__ int scnt[NB];
  __shared__ short flist[NB];
  __shared__ int nfull;
  int tid = threadIdx.x;
  for (int b = tid; b < NB; b += 256) scnt[b] = 0;

  int perBlk = (N_EDGES + gridDim.x - 1) / gridDim.x;
  int e0 = blockIdx.x * perBlk;
  int e1 = min(e0 + perBlk, N_EDGES);
  __syncthreads();

  for (int base = e0; base < e1; base += 256) {
    int e = base + tid;
    if (e < e1) {
      int s = src[e], d = dst[e];
      int b = d >> 8;
      u32 v = ((u32)(d & 255) << 17) | (u32)s;
      int idx = atomicAdd(&scnt[b], 1);
      if (idx < CAP) stage[b * CAP + idx] = v;
      else pairs[atomicAdd(&gcur[b], 1)] = v;     // rare overflow slow path
    }
    __syncthreads();
    if (tid == 0) nfull = 0;
    __syncthreads();
    for (int b = tid; b < NB; b += 256)
      if (scnt[b] >= CAP) flist[atomicAdd(&nfull, 1)] = (short)b;
    __syncthreads();
    int wid = tid >> 6, lane = tid & 63;
    for (int k = wid; k < nfull; k += 4) {
      int b = flist[k];
      int pos;
      if (lane == 0) pos = atomicAdd(&gcur[b], CAP);
      pos = __shfl(pos, 0, 64);
      if (lane < CAP) pairs[pos + lane] = stage[b * CAP + lane];
    }
    __syncthreads();
    for (int k = tid; k < nfull; k += 256) scnt[flist[k]] = 0;
    __syncthreads();
  }
  // final flush of partial buckets
  int wid = tid >> 6, lane = tid & 63;
  for (int b = wid; b < NB; b += 4) {
    int c = scnt[b];
    if (c > 0) {
      if (c > CAP) c = CAP;
      int pos;
      if (lane == 0) pos = atomicAdd(&gcur[b], c);
      pos = __shfl(pos, 0, 64);
      if (lane < c) pairs[pos + lane] = stage[b * CAP + lane];
    }
  }
}

// ---------------- pass 4: per-bucket CSR + deg + dinv ----------------
__global__ __launch_bounds__(256) void k_bcsr(const u32* __restrict__ pairs,
                                              const int* __restrict__ pbase,
                                              const int* __restrict__ bcnt,
                                              int* __restrict__ colsrc,
                                              int* __restrict__ rowptr,
                                              int* __restrict__ deg,
                                              float* __restrict__ dinv) {
  __shared__ int hist[256];
  __shared__ int scan[256];
  __shared__ int excl[256];
  __shared__ int cur[256];
  int tid = threadIdx.x, b = blockIdx.x;
  hist[tid] = 0;
  cur[tid] = 0;
  __syncthreads();
  int base = pbase[b], cnt = bcnt[b];
  for (int k = tid; k < cnt; k += 256)
    atomicAdd(&hist[pairs[base + k] >> 17], 1);
  __syncthreads();
  int c = hist[tid];
  scan[tid] = c;
  __syncthreads();
  for (int off = 1; off < 256; off <<= 1) {
    int v = (tid >= off) ? scan[tid - off] : 0;
    __syncthreads();
    scan[tid] += v;
    __syncthreads();
  }
  int ex = scan[tid] - c;
  excl[tid] = ex;
  int node = b * 256 + tid;
  if (node < N_NODES) {
    deg[node] = c;
    dinv[node] = rsqrtf((float)(c + 1));
    rowptr[node] = base + ex;
  }
  __syncthreads();
  for (int k = tid; k < cnt; k += 256) {
    u32 v = pairs[base + k];
    int dl = v >> 17;
    int s = v & 0x1FFFF;
    colsrc[base + excl[dl] + atomicAdd(&cur[dl], 1)] = s;
  }
}

// ---------------- GEMM1: h1 = x @ W1  [N,512]x[512,16] ----------------
__global__ __launch_bounds__(256) void k_gemm1(const float* __restrict__ x,
                                               const float* __restrict__ W1,
                                               float* __restrict__ h1) {
  __shared__ float Wt[F_H * F_IN];   // 32 KB, transposed [j][k]
  int tid = threadIdx.x;
  for (int idx = tid; idx < F_IN * F_H; idx += 256) {
    int k = idx >> 4, j = idx & 15;
    Wt[j * F_IN + k] = W1[idx];
  }
  __syncthreads();

  int wave = tid >> 6, lane = tid & 63;
  int g = lane & 7, h = lane >> 3;
  int base = (blockIdx.x * 4 + wave) * 16;
  if (base >= N_NODES) return;
  int rowA = base + h * 2, rowB = rowA + 1;

  float accA[16], accB[16];
#pragma unroll
  for (int j = 0; j < 16; j++) { accA[j] = 0.f; accB[j] = 0.f; }

  const float4* xa = (const float4*)(x + (size_t)rowA * F_IN);
  const float4* xb = (const float4*)(x + (size_t)rowB * F_IN);

  for (int t = 0; t < 16; t++) {
    int k0 = g * 4 + t * 32;
    float4 a = xa[g + t * 8];
    float4 b = xb[g + t * 8];
#pragma unroll
    for (int j = 0; j < 16; j++) {
      float4 wv = *(const float4*)(&Wt[j * F_IN + k0]);
      accA[j] += a.x * wv.x + a.y * wv.y + a.z * wv.z + a.w * wv.w;
      accB[j] += b.x * wv.x + b.y * wv.y + b.z * wv.z + b.w * wv.w;
    }
  }
#pragma unroll
  for (int off = 1; off < 8; off <<= 1) {
#pragma unroll
    for (int j = 0; j < 16; j++) {
      accA[j] += __shfl_xor(accA[j], off, 64);
      accB[j] += __shfl_xor(accB[j], off, 64);
    }
  }
  if (g == 0) {
    float4* oa = (float4*)(h1 + (size_t)rowA * F_H);
    oa[0] = make_float4(accA[0], accA[1], accA[2], accA[3]);
    oa[1] = make_float4(accA[4], accA[5], accA[6], accA[7]);
    oa[2] = make_float4(accA[8], accA[9], accA[10], accA[11]);
    oa[3] = make_float4(accA[12], accA[13], accA[14], accA[15]);
    float4* ob = (float4*)(h1 + (size_t)rowB * F_H);
    ob[0] = make_float4(accB[0], accB[1], accB[2], accB[3]);
    ob[1] = make_float4(accB[4], accB[5], accB[6], accB[7]);
    ob[2] = make_float4(accB[8], accB[9], accB[10], accB[11]);
    ob[3] = make_float4(accB[12], accB[13], accB[14], accB[15]);
  }
}

// ---------------- agg layer 1 (+bias+ReLU) ----------------
__global__ __launch_bounds__(256) void k_agg1(const float* __restrict__ h1,
                                              const int* __restrict__ colsrc,
                                              const int* __restrict__ rowptr,
                                              const int* __restrict__ deg,
                                              const float* __restrict__ dinv,
                                              const float* __restrict__ b1,
                                              float* __restrict__ h2) {
  int wid = (blockIdx.x * blockDim.x + threadIdx.x) >> 6;
  if (wid >= N_NODES) return;
  int i = wid;
  int lane = threadIdx.x & 63;
  int j = lane & 15, q = lane >> 4;
  int start = rowptr[i], cnt = deg[i];
  float acc = 0.f;
  for (int e = q; e < cnt; e += 4) {
    int src = colsrc[start + e];
    acc += dinv[src] * h1[src * F_H + j];
  }
  acc += __shfl_xor(acc, 16, 64);
  acc += __shfl_xor(acc, 32, 64);
  if (q == 0) {
    float di = dinv[i];
    float v = di * acc + di * di * h1[i * F_H + j] + b1[j];
    h2[i * F_H + j] = v > 0.f ? v : 0.f;
  }
}

// ---------------- GEMM2: g = h2 @ W2 ----------------
__global__ __launch_bounds__(256) void k_gemm2(const float* __restrict__ h2,
                                               const float* __restrict__ W2,
                                               float* __restrict__ gfeat) {
  __shared__ float w[F_H * F_OUT];
  if (threadIdx.x < F_H * F_OUT) w[threadIdx.x] = W2[threadIdx.x];
  __syncthreads();
  int i = blockIdx.x * blockDim.x + threadIdx.x;
  if (i >= N_NODES) return;
  const float4* hp = (const float4*)(h2 + (size_t)i * F_H);
  float4 h0 = hp[0], h1v = hp[1], h2v = hp[2], h3v = hp[3];
  float hh[16] = {h0.x, h0.y, h0.z, h0.w, h1v.x, h1v.y, h1v.z, h1v.w,
                  h2v.x, h2v.y, h2v.z, h2v.w, h3v.x, h3v.y, h3v.z, h3v.w};
  float o[7] = {0.f, 0.f, 0.f, 0.f, 0.f, 0.f, 0.f};
#pragma unroll
  for (int k = 0; k < 16; k++)
#pragma unroll
    for (int j = 0; j < 7; j++)
      o[j] += hh[k] * w[k * 7 + j];
#pragma unroll
  for (int j = 0; j < 7; j++) gfeat[i * 7 + j] = o[j];
}

// ---------------- agg layer 2 + bias + log_softmax ----------------
__global__ __launch_bounds__(256) void k_agg2(const float* __restrict__ gfeat,
                                              const int* __restrict__ colsrc,
                                              const int* __restrict__ rowptr,
                                              const int* __restrict__ deg,
                                              const float* __restrict__ dinv,
                                              const float* __restrict__ b2,
                                              float* __restrict__ out) {
  int wid = (blockIdx.x * blockDim.x + threadIdx.x) >> 6;
  if (wid >= N_NODES) return;
  int i = wid;
  int lane = threadIdx.x & 63;
  int j = lane & 7, q = lane >> 3;
  bool act = (j < 7);
  int start = rowptr[i], cnt = deg[i];
  float acc = 0.f;
  for (int e = q; e < cnt; e += 8) {
    int src = colsrc[start + e];
    if (act) acc += dinv[src] * gfeat[src * F_OUT + j];
  }
  acc += __shfl_xor(acc, 8, 64);
  acc += __shfl_xor(acc, 16, 64);
  acc += __shfl_xor(acc, 32, 64);
  float v = -1e30f;
  if (act) {
    float di = dinv[i];
    v = di * acc + di * di * gfeat[i * F_OUT + j] + b2[j];
  }
  float m = v;
  m = fmaxf(m, __shfl_xor(m, 1, 64));
  m = fmaxf(m, __shfl_xor(m, 2, 64));
  m = fmaxf(m, __shfl_xor(m, 4, 64));
  float ex = act ? expf(v - m) : 0.f;
  float s = ex;
  s += __shfl_xor(s, 1, 64);
  s += __shfl_xor(s, 2, 64);
  s += __shfl_xor(s, 4, 64);
  if (q == 0 && act) out[i * F_OUT + j] = v - m - logf(s);
}

extern "C" void kernel_launch(void* const* d_in, const int* in_sizes, int n_in,
                              void* d_out, int out_size, void* d_ws, size_t ws_size,
                              hipStream_t stream) {
  const float* x  = (const float*)d_in[0];
  const int*   ei = (const int*)d_in[1];     // [0..E)=src, [E..2E)=dst
  const float* W1 = (const float*)d_in[2];
  const float* b1 = (const float*)d_in[3];
  const float* W2 = (const float*)d_in[4];
  const float* b2 = (const float*)d_in[5];
  float* out = (float*)d_out;

  // workspace layout (<= 30,002,560 bytes, proven available)
  char* base = (char*)d_ws;
  int*   bcnt   = (int*)(base + 0);          // 2048
  int*   pbase  = (int*)(base + 2048);       // 2048
  int*   gcur   = (int*)(base + 4096);       // 2048
  int*   rowptr = (int*)(base + 6144);       // 400128
  int*   deg    = (int*)(base + 406272);     // 400128
  float* dinv   = (float*)(base + 806400);   // 400128
  int*   colsrc = (int*)(base + 1206528);    // 12.9 MB
  // pairs aliases h1/h2/gfeat region (dead until k_gemm1, which runs after k_bcsr)
  u32*   pairs  = (u32*)(base + 14106528);   // 12.9 MB (scratch)
  float* h1     = (float*)(base + 14106528); // 6.4 MB
  float* h2     = (float*)(base + 20506528); // 6.4 MB
  float* gfeat  = (float*)(base + 26906528); // 2.8 MB (ends 29,706,528)

  hipMemsetAsync(bcnt, 0, 2048, stream);

  k_bhist<<<256, 256, 0, stream>>>(ei + N_EDGES, bcnt);
  k_bscan<<<1, 512, 0, stream>>>(bcnt, pbase, gcur);
  k_bin  <<<128, 256, 0, stream>>>(ei, ei + N_EDGES, gcur, pairs);
  k_bcsr <<<NB, 256, 0, stream>>>(pairs, pbase, bcnt, colsrc, rowptr, deg, dinv);

  k_gemm1<<<1563, 256, 0, stream>>>(x, W1, h1);
  k_agg1 <<<N_NODES / 4, 256, 0, stream>>>(h1, colsrc, rowptr, deg, dinv, b1, h2);
  k_gemm2<<<(N_NODES + 255) / 256, 256, 0, stream>>>(h2, W2, gfeat);
  k_agg2 <<<N_NODES / 4, 256, 0, stream>>>(gfeat, colsrc, rowptr, deg, dinv, b2, out);
}

// Round 4
// 297.937 us; speedup vs baseline: 1.9111x; 1.7088x over previous
//
#include <hip/hip_runtime.h>
#include <hip/hip_bf16.h>

#define N_NODES 100000
#define N_EDGES 3200000
#define F_IN    512
#define F_H     16
#define F_OUT   7
#define NB      391      // buckets of 256 dst nodes
#define GPART   512      // partition blocks
#define PER_BLK (N_EDGES / GPART)   // 6250
#define NBG     (NB * GPART)        // 200192 hist cells
#define SCANA_G (NBG / 256)         // 782

typedef unsigned int u32;

// ---------------- pass 1: per-block bucket histogram (no global atomics) ----------------
__global__ __launch_bounds__(256) void k_hist(const int* __restrict__ dst,
                                              int* __restrict__ hist) {
  __shared__ int h[NB];
  int tid = threadIdx.x, blk = blockIdx.x;
  for (int b = tid; b < NB; b += 256) h[b] = 0;
  __syncthreads();
  int e0 = blk * PER_BLK;
  for (int e = e0 + tid; e < e0 + PER_BLK; e += 256)
    atomicAdd(&h[dst[e] >> 8], 1);
  __syncthreads();
  for (int b = tid; b < NB; b += 256)
    hist[b * GPART + blk] = h[b];          // bucket-major for the scan
}

// ---------------- exclusive scan of hist (in place) ----------------
__global__ __launch_bounds__(256) void k_scanA(int* __restrict__ hist,
                                               int* __restrict__ bsums) {
  __shared__ int lds[256];
  int tid = threadIdx.x;
  int i = blockIdx.x * 256 + tid;
  int c = hist[i];
  lds[tid] = c;
  __syncthreads();
  for (int off = 1; off < 256; off <<= 1) {
    int v = (tid >= off) ? lds[tid - off] : 0;
    __syncthreads();
    lds[tid] += v;
    __syncthreads();
  }
  hist[i] = lds[tid] - c;
  if (tid == 255) bsums[blockIdx.x] = lds[tid];
}

__global__ __launch_bounds__(1024) void k_scanB(int* __restrict__ bsums) {
  __shared__ int lds[1024];
  int tid = threadIdx.x;
  int c = (tid < SCANA_G) ? bsums[tid] : 0;
  lds[tid] = c;
  __syncthreads();
  for (int off = 1; off < 1024; off <<= 1) {
    int v = (tid >= off) ? lds[tid - off] : 0;
    __syncthreads();
    lds[tid] += v;
    __syncthreads();
  }
  if (tid < SCANA_G) bsums[tid] = lds[tid] - c;
}

__global__ __launch_bounds__(256) void k_scanC(int* __restrict__ hist,
                                               const int* __restrict__ bsums) {
  int i = blockIdx.x * 256 + threadIdx.x;
  hist[i] += bsums[blockIdx.x];
}

// ---------------- per-bucket base/count for k_bcsr ----------------
__global__ __launch_bounds__(512) void k_extract(const int* __restrict__ hist,
                                                 int* __restrict__ pbase,
                                                 int* __restrict__ bcnt) {
  int b = threadIdx.x;
  if (b < NB) {
    int lo = hist[b * GPART];
    int hi = (b == NB - 1) ? N_EDGES : hist[(b + 1) * GPART];
    pbase[b] = lo;
    bcnt[b] = hi - lo;
  }
}

// ---------------- pass 2: partition scatter (exact offsets, LDS cursors) ----------------
// pack: (dst_local << 17) | src
__global__ __launch_bounds__(256) void k_part(const int* __restrict__ src,
                                              const int* __restrict__ dst,
                                              const int* __restrict__ hist,
                                              u32* __restrict__ pairs) {
  __shared__ int lbase[NB];
  __shared__ int lcur[NB];
  int tid = threadIdx.x, blk = blockIdx.x;
  for (int b = tid; b < NB; b += 256) {
    lbase[b] = hist[b * GPART + blk];
    lcur[b] = 0;
  }
  __syncthreads();
  int e0 = blk * PER_BLK;
  for (int e = e0 + tid; e < e0 + PER_BLK; e += 256) {
    int s = src[e], d = dst[e];
    int b = d >> 8;
    u32 v = ((u32)(d & 255) << 17) | (u32)s;
    int idx = atomicAdd(&lcur[b], 1);
    pairs[lbase[b] + idx] = v;
  }
}

// ---------------- pass 3: per-bucket CSR + deg + dinv ----------------
__global__ __launch_bounds__(256) void k_bcsr(const u32* __restrict__ pairs,
                                              const int* __restrict__ pbase,
                                              const int* __restrict__ bcnt,
                                              int* __restrict__ colsrc,
                                              int* __restrict__ rowptr,
                                              int* __restrict__ deg,
                                              float* __restrict__ dinv) {
  __shared__ int hist[256];
  __shared__ int scan[256];
  __shared__ int excl[256];
  __shared__ int cur[256];
  int tid = threadIdx.x, b = blockIdx.x;
  hist[tid] = 0;
  cur[tid] = 0;
  __syncthreads();
  int base = pbase[b], cnt = bcnt[b];
  for (int k = tid; k < cnt; k += 256)
    atomicAdd(&hist[pairs[base + k] >> 17], 1);
  __syncthreads();
  int c = hist[tid];
  scan[tid] = c;
  __syncthreads();
  for (int off = 1; off < 256; off <<= 1) {
    int v = (tid >= off) ? scan[tid - off] : 0;
    __syncthreads();
    scan[tid] += v;
    __syncthreads();
  }
  int ex = scan[tid] - c;
  excl[tid] = ex;
  int node = b * 256 + tid;
  if (node < N_NODES) {
    deg[node] = c;
    dinv[node] = rsqrtf((float)(c + 1));
    rowptr[node] = base + ex;
  }
  __syncthreads();
  for (int k = tid; k < cnt; k += 256) {
    u32 v = pairs[base + k];
    int dl = v >> 17;
    int s = v & 0x1FFFF;
    colsrc[base + excl[dl] + atomicAdd(&cur[dl], 1)] = s;
  }
}

// ---------------- GEMM1: h1 = x @ W1  [N,512]x[512,16] ----------------
__global__ __launch_bounds__(256) void k_gemm1(const float* __restrict__ x,
                                               const float* __restrict__ W1,
                                               float* __restrict__ h1) {
  __shared__ float Wt[F_H * F_IN];   // 32 KB, transposed [j][k]
  int tid = threadIdx.x;
  for (int idx = tid; idx < F_IN * F_H; idx += 256) {
    int k = idx >> 4, j = idx & 15;
    Wt[j * F_IN + k] = W1[idx];
  }
  __syncthreads();

  int wave = tid >> 6, lane = tid & 63;
  int g = lane & 7, h = lane >> 3;
  int base = (blockIdx.x * 4 + wave) * 16;
  if (base >= N_NODES) return;
  int rowA = base + h * 2, rowB = rowA + 1;

  float accA[16], accB[16];
#pragma unroll
  for (int j = 0; j < 16; j++) { accA[j] = 0.f; accB[j] = 0.f; }

  const float4* xa = (const float4*)(x + (size_t)rowA * F_IN);
  const float4* xb = (const float4*)(x + (size_t)rowB * F_IN);

  for (int t = 0; t < 16; t++) {
    int k0 = g * 4 + t * 32;
    float4 a = xa[g + t * 8];
    float4 b = xb[g + t * 8];
#pragma unroll
    for (int j = 0; j < 16; j++) {
      float4 wv = *(const float4*)(&Wt[j * F_IN + k0]);
      accA[j] += a.x * wv.x + a.y * wv.y + a.z * wv.z + a.w * wv.w;
      accB[j] += b.x * wv.x + b.y * wv.y + b.z * wv.z + b.w * wv.w;
    }
  }
#pragma unroll
  for (int off = 1; off < 8; off <<= 1) {
#pragma unroll
    for (int j = 0; j < 16; j++) {
      accA[j] += __shfl_xor(accA[j], off, 64);
      accB[j] += __shfl_xor(accB[j], off, 64);
    }
  }
  if (g == 0) {
    float4* oa = (float4*)(h1 + (size_t)rowA * F_H);
    oa[0] = make_float4(accA[0], accA[1], accA[2], accA[3]);
    oa[1] = make_float4(accA[4], accA[5], accA[6], accA[7]);
    oa[2] = make_float4(accA[8], accA[9], accA[10], accA[11]);
    oa[3] = make_float4(accA[12], accA[13], accA[14], accA[15]);
    float4* ob = (float4*)(h1 + (size_t)rowB * F_H);
    ob[0] = make_float4(accB[0], accB[1], accB[2], accB[3]);
    ob[1] = make_float4(accB[4], accB[5], accB[6], accB[7]);
    ob[2] = make_float4(accB[8], accB[9], accB[10], accB[11]);
    ob[3] = make_float4(accB[12], accB[13], accB[14], accB[15]);
  }
}

// ---------------- agg layer 1 (+bias+ReLU) ----------------
__global__ __launch_bounds__(256) void k_agg1(const float* __restrict__ h1,
                                              const int* __restrict__ colsrc,
                                              const int* __restrict__ rowptr,
                                              const int* __restrict__ deg,
                                              const float* __restrict__ dinv,
                                              const float* __restrict__ b1,
                                              float* __restrict__ h2) {
  int wid = (blockIdx.x * blockDim.x + threadIdx.x) >> 6;
  if (wid >= N_NODES) return;
  int i = wid;
  int lane = threadIdx.x & 63;
  int j = lane & 15, q = lane >> 4;
  int start = rowptr[i], cnt = deg[i];
  float acc = 0.f;
  for (int e = q; e < cnt; e += 4) {
    int src = colsrc[start + e];
    acc += dinv[src] * h1[src * F_H + j];
  }
  acc += __shfl_xor(acc, 16, 64);
  acc += __shfl_xor(acc, 32, 64);
  if (q == 0) {
    float di = dinv[i];
    float v = di * acc + di * di * h1[i * F_H + j] + b1[j];
    h2[i * F_H + j] = v > 0.f ? v : 0.f;
  }
}

// ---------------- GEMM2: g = h2 @ W2 ----------------
__global__ __launch_bounds__(256) void k_gemm2(const float* __restrict__ h2,
                                               const float* __restrict__ W2,
                                               float* __restrict__ gfeat) {
  __shared__ float w[F_H * F_OUT];
  if (threadIdx.x < F_H * F_OUT) w[threadIdx.x] = W2[threadIdx.x];
  __syncthreads();
  int i = blockIdx.x * blockDim.x + threadIdx.x;
  if (i >= N_NODES) return;
  const float4* hp = (const float4*)(h2 + (size_t)i * F_H);
  float4 h0 = hp[0], h1v = hp[1], h2v = hp[2], h3v = hp[3];
  float hh[16] = {h0.x, h0.y, h0.z, h0.w, h1v.x, h1v.y, h1v.z, h1v.w,
                  h2v.x, h2v.y, h2v.z, h2v.w, h3v.x, h3v.y, h3v.z, h3v.w};
  float o[7] = {0.f, 0.f, 0.f, 0.f, 0.f, 0.f, 0.f};
#pragma unroll
  for (int k = 0; k < 16; k++)
#pragma unroll
    for (int j = 0; j < 7; j++)
      o[j] += hh[k] * w[k * 7 + j];
#pragma unroll
  for (int j = 0; j < 7; j++) gfeat[i * 7 + j] = o[j];
}

// ---------------- agg layer 2 + bias + log_softmax ----------------
__global__ __launch_bounds__(256) void k_agg2(const float* __restrict__ gfeat,
                                              const int* __restrict__ colsrc,
                                              const int* __restrict__ rowptr,
                                              const int* __restrict__ deg,
                                              const float* __restrict__ dinv,
                                              const float* __restrict__ b2,
                                              float* __restrict__ out) {
  int wid = (blockIdx.x * blockDim.x + threadIdx.x) >> 6;
  if (wid >= N_NODES) return;
  int i = wid;
  int lane = threadIdx.x & 63;
  int j = lane & 7, q = lane >> 3;
  bool act = (j < 7);
  int start = rowptr[i], cnt = deg[i];
  float acc = 0.f;
  for (int e = q; e < cnt; e += 8) {
    int src = colsrc[start + e];
    if (act) acc += dinv[src] * gfeat[src * F_OUT + j];
  }
  acc += __shfl_xor(acc, 8, 64);
  acc += __shfl_xor(acc, 16, 64);
  acc += __shfl_xor(acc, 32, 64);
  float v = -1e30f;
  if (act) {
    float di = dinv[i];
    v = di * acc + di * di * gfeat[i * F_OUT + j] + b2[j];
  }
  float m = v;
  m = fmaxf(m, __shfl_xor(m, 1, 64));
  m = fmaxf(m, __shfl_xor(m, 2, 64));
  m = fmaxf(m, __shfl_xor(m, 4, 64));
  float ex = act ? expf(v - m) : 0.f;
  float s = ex;
  s += __shfl_xor(s, 1, 64);
  s += __shfl_xor(s, 2, 64);
  s += __shfl_xor(s, 4, 64);
  if (q == 0 && act) out[i * F_OUT + j] = v - m - logf(s);
}

extern "C" void kernel_launch(void* const* d_in, const int* in_sizes, int n_in,
                              void* d_out, int out_size, void* d_ws, size_t ws_size,
                              hipStream_t stream) {
  const float* x  = (const float*)d_in[0];
  const int*   ei = (const int*)d_in[1];     // [0..E)=src, [E..2E)=dst
  const float* W1 = (const float*)d_in[2];
  const float* b1 = (const float*)d_in[3];
  const float* W2 = (const float*)d_in[4];
  const float* b2 = (const float*)d_in[5];
  float* out = (float*)d_out;

  // workspace layout (27.6 MB; proven >=30.0 MB available)
  char* base = (char*)d_ws;
  int*   hist   = (int*)(base + 0);          //  800768  (NBG*4)
  int*   bsums  = (int*)(base + 800768);     //  4096
  int*   pbase  = (int*)(base + 804864);     //  2048
  int*   bcnt   = (int*)(base + 806912);     //  2048
  int*   rowptr = (int*)(base + 808960);     //  400128
  int*   deg    = (int*)(base + 1209088);    //  400128
  float* dinv   = (float*)(base + 1609216);  //  400128
  int*   colsrc = (int*)(base + 2009344);    //  12.8 MB   (ends 14,809,344)
  // pairs (12.8 MB) aliases h1+h2; dead after k_bcsr, before k_gemm1.
  u32*   pairs  = (u32*)(base + 14809344);
  float* h1     = (float*)(base + 14809344); //  6.4 MB
  float* gfeat  = (float*)(base + 14809344); //  2.8 MB (aliases h1: h1 dead before k_gemm2 writes gfeat)
  float* h2     = (float*)(base + 21209344); //  6.4 MB   (ends 27,609,344)

  k_hist   <<<GPART, 256, 0, stream>>>(ei + N_EDGES, hist);
  k_scanA  <<<SCANA_G, 256, 0, stream>>>(hist, bsums);
  k_scanB  <<<1, 1024, 0, stream>>>(bsums);
  k_scanC  <<<SCANA_G, 256, 0, stream>>>(hist, bsums);
  k_extract<<<1, 512, 0, stream>>>(hist, pbase, bcnt);
  k_part   <<<GPART, 256, 0, stream>>>(ei, ei + N_EDGES, hist, pairs);
  k_bcsr   <<<NB, 256, 0, stream>>>(pairs, pbase, bcnt, colsrc, rowptr, deg, dinv);

  k_gemm1  <<<1563, 256, 0, stream>>>(x, W1, h1);
  k_agg1   <<<N_NODES / 4, 256, 0, stream>>>(h1, colsrc, rowptr, deg, dinv, b1, h2);
  k_gemm2  <<<(N_NODES + 255) / 256, 256, 0, stream>>>(h2, W2, gfeat);
  k_agg2   <<<N_NODES / 4, 256, 0, stream>>>(gfeat, colsrc, rowptr, deg, dinv, b2, out);
}

// Round 5
// 228.420 us; speedup vs baseline: 2.4927x; 1.3043x over previous
//
#include <hip/hip_runtime.h>
#include <hip/hip_bf16.h>

#define N_NODES 100000
#define N_EDGES 3200000
#define F_IN    512
#define F_H     16
#define F_OUT   7
#define NB      391                 // buckets of 256 dst nodes
#define GPART   512                 // partition blocks
#define PER_BLK 6256                // divisible by 4; 512*6256 >= 3.2M (last block short)
#define NBG     (NB * GPART)        // 200192 hist cells
#define SCANA_G (NBG / 256)         // 782
#define GEMM_BLKS 782               // ceil(100000 / 128) rows, 128 rows/block

typedef unsigned int u32;

// ============ fused: bucket histogram (blocks < GPART) + GEMM1 (rest) ============
// GEMM1: h1 = x @ W1, [N,512]x[512,16]. 4 waves/block, 32 rows/wave, 4 rows/thread.
__global__ __launch_bounds__(256) void k_hist_gemm1(const int* __restrict__ dst,
                                                    int* __restrict__ hist,
                                                    const float* __restrict__ x,
                                                    const float* __restrict__ W1,
                                                    float* __restrict__ h1) {
  __shared__ __align__(16) char smem[F_H * F_IN * 4];   // 32 KB shared by both paths
  int tid = threadIdx.x;

  if (blockIdx.x < GPART) {
    // ---- histogram path ----
    int* h = (int*)smem;
    for (int b = tid; b < NB; b += 256) h[b] = 0;
    __syncthreads();
    int e0 = blockIdx.x * PER_BLK;
    int n = min(PER_BLK, N_EDGES - e0);          // always a multiple of 4
    const int4* d4 = (const int4*)(dst + e0);
    for (int i = tid; i < (n >> 2); i += 256) {
      int4 d = d4[i];
      atomicAdd(&h[d.x >> 8], 1);
      atomicAdd(&h[d.y >> 8], 1);
      atomicAdd(&h[d.z >> 8], 1);
      atomicAdd(&h[d.w >> 8], 1);
    }
    __syncthreads();
    for (int b = tid; b < NB; b += 256) hist[b * GPART + blockIdx.x] = h[b];
    return;
  }

  // ---- GEMM1 path ----
  float* Wt = (float*)smem;                      // [16][512] transposed
  for (int idx = tid; idx < F_IN * F_H; idx += 256) {
    int k = idx >> 4, j = idx & 15;
    Wt[j * F_IN + k] = W1[idx];
  }
  __syncthreads();

  int gb = blockIdx.x - GPART;
  int wave = tid >> 6, lane = tid & 63;
  int g = lane & 7, h = lane >> 3;
  int base = (gb * 4 + wave) * 32;
  int row0 = base + h * 4;

  const float* xp[4];
  bool rv[4];
#pragma unroll
  for (int rr = 0; rr < 4; rr++) {
    int r = row0 + rr;
    rv[rr] = r < N_NODES;
    xp[rr] = x + (size_t)(rv[rr] ? r : 0) * F_IN;
  }

  float acc[4][16];
#pragma unroll
  for (int rr = 0; rr < 4; rr++)
#pragma unroll
    for (int j = 0; j < 16; j++) acc[rr][j] = 0.f;

  for (int t = 0; t < 16; t++) {
    int k0 = g * 4 + t * 32;
    float4 a0 = ((const float4*)xp[0])[g + t * 8];
    float4 a1 = ((const float4*)xp[1])[g + t * 8];
    float4 a2 = ((const float4*)xp[2])[g + t * 8];
    float4 a3 = ((const float4*)xp[3])[g + t * 8];
#pragma unroll
    for (int j = 0; j < 16; j++) {
      float4 wv = *(const float4*)(&Wt[j * F_IN + k0]);
      acc[0][j] += a0.x * wv.x + a0.y * wv.y + a0.z * wv.z + a0.w * wv.w;
      acc[1][j] += a1.x * wv.x + a1.y * wv.y + a1.z * wv.z + a1.w * wv.w;
      acc[2][j] += a2.x * wv.x + a2.y * wv.y + a2.z * wv.z + a2.w * wv.w;
      acc[3][j] += a3.x * wv.x + a3.y * wv.y + a3.z * wv.z + a3.w * wv.w;
    }
  }
#pragma unroll
  for (int off = 1; off < 8; off <<= 1)
#pragma unroll
    for (int rr = 0; rr < 4; rr++)
#pragma unroll
      for (int j = 0; j < 16; j++)
        acc[rr][j] += __shfl_xor(acc[rr][j], off, 64);

  if (g == 0) {
#pragma unroll
    for (int rr = 0; rr < 4; rr++) {
      if (!rv[rr]) continue;
      float4* o = (float4*)(h1 + (size_t)(row0 + rr) * F_H);
      o[0] = make_float4(acc[rr][0], acc[rr][1], acc[rr][2], acc[rr][3]);
      o[1] = make_float4(acc[rr][4], acc[rr][5], acc[rr][6], acc[rr][7]);
      o[2] = make_float4(acc[rr][8], acc[rr][9], acc[rr][10], acc[rr][11]);
      o[3] = make_float4(acc[rr][12], acc[rr][13], acc[rr][14], acc[rr][15]);
    }
  }
}

// ---------------- exclusive scan of hist (in place) ----------------
__global__ __launch_bounds__(256) void k_scanA(int* __restrict__ hist,
                                               int* __restrict__ bsums) {
  __shared__ int lds[256];
  int tid = threadIdx.x;
  int i = blockIdx.x * 256 + tid;
  int c = hist[i];
  lds[tid] = c;
  __syncthreads();
  for (int off = 1; off < 256; off <<= 1) {
    int v = (tid >= off) ? lds[tid - off] : 0;
    __syncthreads();
    lds[tid] += v;
    __syncthreads();
  }
  hist[i] = lds[tid] - c;
  if (tid == 255) bsums[blockIdx.x] = lds[tid];
}

__global__ __launch_bounds__(1024) void k_scanB(int* __restrict__ bsums) {
  __shared__ int lds[1024];
  int tid = threadIdx.x;
  int c = (tid < SCANA_G) ? bsums[tid] : 0;
  lds[tid] = c;
  __syncthreads();
  for (int off = 1; off < 1024; off <<= 1) {
    int v = (tid >= off) ? lds[tid - off] : 0;
    __syncthreads();
    lds[tid] += v;
    __syncthreads();
  }
  if (tid < SCANA_G) bsums[tid] = lds[tid] - c;
}

__global__ __launch_bounds__(256) void k_scanC(int* __restrict__ hist,
                                               const int* __restrict__ bsums) {
  int i = blockIdx.x * 256 + threadIdx.x;
  hist[i] += bsums[blockIdx.x];
}

// ---------------- partition scatter (exact offsets, LDS cursors) ----------------
// pack: (dst_local << 17) | src
__global__ __launch_bounds__(256) void k_part(const int* __restrict__ src,
                                              const int* __restrict__ dst,
                                              const int* __restrict__ hist,
                                              u32* __restrict__ pairs) {
  __shared__ int lbase[NB];
  __shared__ int lcur[NB];
  int tid = threadIdx.x, blk = blockIdx.x;
  for (int b = tid; b < NB; b += 256) {
    lbase[b] = hist[b * GPART + blk];
    lcur[b] = 0;
  }
  __syncthreads();
  int e0 = blk * PER_BLK;
  int n = min(PER_BLK, N_EDGES - e0);            // multiple of 4
  const int4* s4 = (const int4*)(src + e0);
  const int4* d4 = (const int4*)(dst + e0);
  for (int i = tid; i < (n >> 2); i += 256) {
    int4 sv = s4[i];
    int4 dv = d4[i];
    {
      int b = dv.x >> 8;
      u32 v = ((u32)(dv.x & 255) << 17) | (u32)sv.x;
      pairs[lbase[b] + atomicAdd(&lcur[b], 1)] = v;
    }
    {
      int b = dv.y >> 8;
      u32 v = ((u32)(dv.y & 255) << 17) | (u32)sv.y;
      pairs[lbase[b] + atomicAdd(&lcur[b], 1)] = v;
    }
    {
      int b = dv.z >> 8;
      u32 v = ((u32)(dv.z & 255) << 17) | (u32)sv.z;
      pairs[lbase[b] + atomicAdd(&lcur[b], 1)] = v;
    }
    {
      int b = dv.w >> 8;
      u32 v = ((u32)(dv.w & 255) << 17) | (u32)sv.w;
      pairs[lbase[b] + atomicAdd(&lcur[b], 1)] = v;
    }
  }
}

// ---------------- per-bucket CSR + deg + dinv ----------------
__global__ __launch_bounds__(512) void k_bcsr(const u32* __restrict__ pairs,
                                              const int* __restrict__ hist,
                                              int* __restrict__ colsrc,
                                              int* __restrict__ rowptr,
                                              int* __restrict__ deg,
                                              float* __restrict__ dinv) {
  __shared__ int hist256[256];
  __shared__ int scan[256];
  __shared__ int excl[256];
  __shared__ int cur[256];
  int tid = threadIdx.x, b = blockIdx.x;
  if (tid < 256) { hist256[tid] = 0; cur[tid] = 0; }
  __syncthreads();
  int base = hist[b * GPART];
  int end  = (b == NB - 1) ? N_EDGES : hist[(b + 1) * GPART];
  int cnt  = end - base;
  for (int k = tid; k < cnt; k += 512)
    atomicAdd(&hist256[pairs[base + k] >> 17], 1);
  __syncthreads();
  if (tid < 256) scan[tid] = hist256[tid];
  __syncthreads();
  for (int off = 1; off < 256; off <<= 1) {
    int v = 0;
    if (tid < 256 && tid >= off) v = scan[tid - off];
    __syncthreads();
    if (tid < 256) scan[tid] += v;
    __syncthreads();
  }
  if (tid < 256) {
    int c = hist256[tid];
    int ex = scan[tid] - c;
    excl[tid] = ex;
    int node = b * 256 + tid;
    if (node < N_NODES) {
      deg[node] = c;
      dinv[node] = rsqrtf((float)(c + 1));
      rowptr[node] = base + ex;
    }
  }
  __syncthreads();
  for (int k = tid; k < cnt; k += 512) {
    u32 v = pairs[base + k];
    int dl = v >> 17;
    colsrc[base + excl[dl] + atomicAdd(&cur[dl], 1)] = (int)(v & 0x1FFFF);
  }
}

// ============ fused agg1 (+bias+ReLU) + GEMM2 -> gfeat8 (padded to 8) ============
// wave per node: c = lane&3 (float4 chunk of the 16-wide h1 row), q = lane>>2 (16 edge slots)
__global__ __launch_bounds__(256) void k_agg1g2(const float* __restrict__ h1,
                                                const int* __restrict__ colsrc,
                                                const int* __restrict__ rowptr,
                                                const int* __restrict__ deg,
                                                const float* __restrict__ dinv,
                                                const float* __restrict__ b1,
                                                const float* __restrict__ W2,
                                                float* __restrict__ gfeat8) {
  __shared__ float hrow[4][16];
  int tid = threadIdx.x;
  int wv = tid >> 6, lane = tid & 63;
  int c = lane & 3, q = lane >> 2;
  int i = blockIdx.x * 4 + wv;                   // grid is exact: 25000 blocks

  // per-lane W2 column (j' = lane & 7)
  int jp = lane & 7;
  bool jv = jp < 7;
  float wcol[16];
#pragma unroll
  for (int k = 0; k < 16; k++) wcol[k] = jv ? W2[k * 7 + jp] : 0.f;

  int start = rowptr[i], cnt = deg[i];
  float4 acc = make_float4(0.f, 0.f, 0.f, 0.f);
  for (int e = q; e < cnt; e += 16) {
    int src = colsrc[start + e];
    float di = dinv[src];
    float4 v = *(const float4*)(h1 + (size_t)src * F_H + c * 4);
    acc.x += di * v.x; acc.y += di * v.y; acc.z += di * v.z; acc.w += di * v.w;
  }
#pragma unroll
  for (int off = 4; off < 64; off <<= 1) {
    acc.x += __shfl_xor(acc.x, off, 64);
    acc.y += __shfl_xor(acc.y, off, 64);
    acc.z += __shfl_xor(acc.z, off, 64);
    acc.w += __shfl_xor(acc.w, off, 64);
  }
  float di = dinv[i];
  float4 sv = *(const float4*)(h1 + (size_t)i * F_H + c * 4);
  float4 bb = *(const float4*)(b1 + c * 4);
  float4 h2c;
  h2c.x = fmaxf(di * acc.x + di * di * sv.x + bb.x, 0.f);
  h2c.y = fmaxf(di * acc.y + di * di * sv.y + bb.y, 0.f);
  h2c.z = fmaxf(di * acc.z + di * di * sv.z + bb.z, 0.f);
  h2c.w = fmaxf(di * acc.w + di * di * sv.w + bb.w, 0.f);

  if (q == 0) *(float4*)(&hrow[wv][c * 4]) = h2c;
  __syncthreads();

  float o = 0.f;
#pragma unroll
  for (int k = 0; k < 16; k++) o += hrow[wv][k] * wcol[k];

  if (lane < 8) gfeat8[(size_t)i * 8 + jp] = jv ? o : 0.f;
}

// ============ agg2 + bias + log_softmax -> out [N,7] ============
// wave per node: c = lane&3 (float2 chunk of padded 8-wide row), q = lane>>2 (16 slots)
__global__ __launch_bounds__(256) void k_agg2(const float* __restrict__ gfeat8,
                                              const int* __restrict__ colsrc,
                                              const int* __restrict__ rowptr,
                                              const int* __restrict__ deg,
                                              const float* __restrict__ dinv,
                                              const float* __restrict__ b2,
                                              float* __restrict__ out) {
  int tid = threadIdx.x;
  int wv = tid >> 6, lane = tid & 63;
  int c = lane & 3, q = lane >> 2;
  int i = blockIdx.x * 4 + wv;                   // exact grid

  float bx = b2[c * 2];
  float by = (c * 2 + 1 < 7) ? b2[c * 2 + 1] : 0.f;
  bool yv = (c < 3);

  int start = rowptr[i], cnt = deg[i];
  float ax = 0.f, ay = 0.f;
  for (int e = q; e < cnt; e += 16) {
    int src = colsrc[start + e];
    float di = dinv[src];
    float2 v = *(const float2*)(gfeat8 + (size_t)src * 8 + c * 2);
    ax += di * v.x; ay += di * v.y;
  }
#pragma unroll
  for (int off = 4; off < 64; off <<= 1) {
    ax += __shfl_xor(ax, off, 64);
    ay += __shfl_xor(ay, off, 64);
  }
  float di = dinv[i];
  float2 sv = *(const float2*)(gfeat8 + (size_t)i * 8 + c * 2);
  float vx = di * ax + di * di * sv.x + bx;
  float vy = di * ay + di * di * sv.y + by;

  float m = yv ? fmaxf(vx, vy) : vx;
  m = fmaxf(m, __shfl_xor(m, 1, 64));
  m = fmaxf(m, __shfl_xor(m, 2, 64));
  float s = __expf(vx - m) + (yv ? __expf(vy - m) : 0.f);
  s += __shfl_xor(s, 1, 64);
  s += __shfl_xor(s, 2, 64);
  float ls = logf(s);

  if (q == 0) {
    out[(size_t)i * 7 + c * 2] = vx - m - ls;
    if (yv) out[(size_t)i * 7 + c * 2 + 1] = vy - m - ls;
  }
}

extern "C" void kernel_launch(void* const* d_in, const int* in_sizes, int n_in,
                              void* d_out, int out_size, void* d_ws, size_t ws_size,
                              hipStream_t stream) {
  const float* x  = (const float*)d_in[0];
  const int*   ei = (const int*)d_in[1];     // [0..E)=src, [E..2E)=dst (int32)
  const float* W1 = (const float*)d_in[2];
  const float* b1 = (const float*)d_in[3];
  const float* W2 = (const float*)d_in[4];
  const float* b2 = (const float*)d_in[5];
  float* out = (float*)d_out;

  // workspace layout (~37.2 MB; d_ws is ~800 MB per harness fill size)
  char* base = (char*)d_ws;
  int*   hist   = (int*)(base + 0);          //  800,768  (NBG*4)
  int*   bsums  = (int*)(base + 800768);     //  4,096
  int*   rowptr = (int*)(base + 804864);     //  400,128
  int*   deg    = (int*)(base + 1204992);    //  400,128
  float* dinv   = (float*)(base + 1605120);  //  400,128
  int*   colsrc = (int*)(base + 2005248);    //  12.8 MB  (ends 14,805,248)
  u32*   pairs  = (u32*)(base + 14805248);   //  12.8 MB  (ends 27,605,248)
  float* h1     = (float*)(base + 27605248); //  6.4 MB   (ends 34,005,248)
  float* gfeat8 = (float*)(base + 34005248); //  3.2 MB   (ends 37,205,248)

  k_hist_gemm1<<<GPART + GEMM_BLKS, 256, 0, stream>>>(ei + N_EDGES, hist, x, W1, h1);
  k_scanA     <<<SCANA_G, 256, 0, stream>>>(hist, bsums);
  k_scanB     <<<1, 1024, 0, stream>>>(bsums);
  k_scanC     <<<SCANA_G, 256, 0, stream>>>(hist, bsums);
  k_part      <<<GPART, 256, 0, stream>>>(ei, ei + N_EDGES, hist, pairs);
  k_bcsr      <<<NB, 512, 0, stream>>>(pairs, hist, colsrc, rowptr, deg, dinv);
  k_agg1g2    <<<N_NODES / 4, 256, 0, stream>>>(h1, colsrc, rowptr, deg, dinv, b1, W2, gfeat8);
  k_agg2      <<<N_NODES / 4, 256, 0, stream>>>(gfeat8, colsrc, rowptr, deg, dinv, b2, out);
}

// Round 6
// 222.370 us; speedup vs baseline: 2.5605x; 1.0272x over previous
//
#include <hip/hip_runtime.h>
#include <hip/hip_bf16.h>

#define N_NODES 100000
#define N_EDGES 3200000
#define F_IN    512
#define F_H     16
#define F_OUT   7
#define NB      391                 // buckets of 256 dst nodes
#define GPART   512                 // partition blocks
#define PER_BLK 6256                // divisible by 4; 512*6256 >= 3.2M (last block short)
#define NBG     (NB * GPART)        // 200192 hist cells
#define SCANA_G (NBG / 256)         // 782
#define GEMM_BLKS 782               // 128 rows/block

typedef unsigned int u32;

static __device__ __forceinline__ float bflo(u32 u) { return __uint_as_float(u << 16); }
static __device__ __forceinline__ float bfhi(u32 u) { return __uint_as_float(u & 0xFFFF0000u); }
static __device__ __forceinline__ unsigned short f2bf(float f) {
  u32 x = __float_as_uint(f);
  x += 0x7FFF + ((x >> 16) & 1);    // round-to-nearest-even (finite values)
  return (unsigned short)(x >> 16);
}

// ============ fused: bucket histogram (blocks < GPART) + GEMM1 (rest) ============
__global__ __launch_bounds__(256) void k_hist_gemm1(const int* __restrict__ dst,
                                                    int* __restrict__ hist,
                                                    const float* __restrict__ x,
                                                    const float* __restrict__ W1,
                                                    float* __restrict__ h1) {
  __shared__ __align__(16) char smem[F_H * F_IN * 4];   // 32 KB shared by both paths
  int tid = threadIdx.x;

  if (blockIdx.x < GPART) {
    int* h = (int*)smem;
    for (int b = tid; b < NB; b += 256) h[b] = 0;
    __syncthreads();
    int e0 = blockIdx.x * PER_BLK;
    int n = min(PER_BLK, N_EDGES - e0);          // multiple of 4
    const int4* d4 = (const int4*)(dst + e0);
    for (int i = tid; i < (n >> 2); i += 256) {
      int4 d = d4[i];
      atomicAdd(&h[d.x >> 8], 1);
      atomicAdd(&h[d.y >> 8], 1);
      atomicAdd(&h[d.z >> 8], 1);
      atomicAdd(&h[d.w >> 8], 1);
    }
    __syncthreads();
    for (int b = tid; b < NB; b += 256) hist[b * GPART + blockIdx.x] = h[b];
    return;
  }

  float* Wt = (float*)smem;                      // [16][512] transposed
  for (int idx = tid; idx < F_IN * F_H; idx += 256) {
    int k = idx >> 4, j = idx & 15;
    Wt[j * F_IN + k] = W1[idx];
  }
  __syncthreads();

  int gb = blockIdx.x - GPART;
  int wave = tid >> 6, lane = tid & 63;
  int g = lane & 7, h = lane >> 3;
  int base = (gb * 4 + wave) * 32;
  int row0 = base + h * 4;

  const float* xp[4];
  bool rv[4];
#pragma unroll
  for (int rr = 0; rr < 4; rr++) {
    int r = row0 + rr;
    rv[rr] = r < N_NODES;
    xp[rr] = x + (size_t)(rv[rr] ? r : 0) * F_IN;
  }

  float acc[4][16];
#pragma unroll
  for (int rr = 0; rr < 4; rr++)
#pragma unroll
    for (int j = 0; j < 16; j++) acc[rr][j] = 0.f;

  for (int t = 0; t < 16; t++) {
    int k0 = g * 4 + t * 32;
    float4 a0 = ((const float4*)xp[0])[g + t * 8];
    float4 a1 = ((const float4*)xp[1])[g + t * 8];
    float4 a2 = ((const float4*)xp[2])[g + t * 8];
    float4 a3 = ((const float4*)xp[3])[g + t * 8];
#pragma unroll
    for (int j = 0; j < 16; j++) {
      float4 wv = *(const float4*)(&Wt[j * F_IN + k0]);
      acc[0][j] += a0.x * wv.x + a0.y * wv.y + a0.z * wv.z + a0.w * wv.w;
      acc[1][j] += a1.x * wv.x + a1.y * wv.y + a1.z * wv.z + a1.w * wv.w;
      acc[2][j] += a2.x * wv.x + a2.y * wv.y + a2.z * wv.z + a2.w * wv.w;
      acc[3][j] += a3.x * wv.x + a3.y * wv.y + a3.z * wv.z + a3.w * wv.w;
    }
  }
#pragma unroll
  for (int off = 1; off < 8; off <<= 1)
#pragma unroll
    for (int rr = 0; rr < 4; rr++)
#pragma unroll
      for (int j = 0; j < 16; j++)
        acc[rr][j] += __shfl_xor(acc[rr][j], off, 64);

  if (g == 0) {
#pragma unroll
    for (int rr = 0; rr < 4; rr++) {
      if (!rv[rr]) continue;
      float4* o = (float4*)(h1 + (size_t)(row0 + rr) * F_H);
      o[0] = make_float4(acc[rr][0], acc[rr][1], acc[rr][2], acc[rr][3]);
      o[1] = make_float4(acc[rr][4], acc[rr][5], acc[rr][6], acc[rr][7]);
      o[2] = make_float4(acc[rr][8], acc[rr][9], acc[rr][10], acc[rr][11]);
      o[3] = make_float4(acc[rr][12], acc[rr][13], acc[rr][14], acc[rr][15]);
    }
  }
}

// ---------------- exclusive scan of hist (in place) ----------------
__global__ __launch_bounds__(256) void k_scanA(int* __restrict__ hist,
                                               int* __restrict__ bsums) {
  __shared__ int lds[256];
  int tid = threadIdx.x;
  int i = blockIdx.x * 256 + tid;
  int c = hist[i];
  lds[tid] = c;
  __syncthreads();
  for (int off = 1; off < 256; off <<= 1) {
    int v = (tid >= off) ? lds[tid - off] : 0;
    __syncthreads();
    lds[tid] += v;
    __syncthreads();
  }
  hist[i] = lds[tid] - c;
  if (tid == 255) bsums[blockIdx.x] = lds[tid];
}

__global__ __launch_bounds__(1024) void k_scanB(int* __restrict__ bsums) {
  __shared__ int lds[1024];
  int tid = threadIdx.x;
  int c = (tid < SCANA_G) ? bsums[tid] : 0;
  lds[tid] = c;
  __syncthreads();
  for (int off = 1; off < 1024; off <<= 1) {
    int v = (tid >= off) ? lds[tid - off] : 0;
    __syncthreads();
    lds[tid] += v;
    __syncthreads();
  }
  if (tid < SCANA_G) bsums[tid] = lds[tid] - c;
}

__global__ __launch_bounds__(256) void k_scanC(int* __restrict__ hist,
                                               const int* __restrict__ bsums) {
  int i = blockIdx.x * 256 + threadIdx.x;
  hist[i] += bsums[blockIdx.x];
}

// ---------------- partition scatter (exact offsets, LDS cursors) ----------------
__global__ __launch_bounds__(256) void k_part(const int* __restrict__ src,
                                              const int* __restrict__ dst,
                                              const int* __restrict__ hist,
                                              u32* __restrict__ pairs) {
  __shared__ int lbase[NB];
  __shared__ int lcur[NB];
  int tid = threadIdx.x, blk = blockIdx.x;
  for (int b = tid; b < NB; b += 256) {
    lbase[b] = hist[b * GPART + blk];
    lcur[b] = 0;
  }
  __syncthreads();
  int e0 = blk * PER_BLK;
  int n = min(PER_BLK, N_EDGES - e0);            // multiple of 4
  const int4* s4 = (const int4*)(src + e0);
  const int4* d4 = (const int4*)(dst + e0);
  for (int i = tid; i < (n >> 2); i += 256) {
    int4 sv = s4[i];
    int4 dv = d4[i];
    { int b = dv.x >> 8; u32 v = ((u32)(dv.x & 255) << 17) | (u32)sv.x;
      pairs[lbase[b] + atomicAdd(&lcur[b], 1)] = v; }
    { int b = dv.y >> 8; u32 v = ((u32)(dv.y & 255) << 17) | (u32)sv.y;
      pairs[lbase[b] + atomicAdd(&lcur[b], 1)] = v; }
    { int b = dv.z >> 8; u32 v = ((u32)(dv.z & 255) << 17) | (u32)sv.z;
      pairs[lbase[b] + atomicAdd(&lcur[b], 1)] = v; }
    { int b = dv.w >> 8; u32 v = ((u32)(dv.w & 255) << 17) | (u32)sv.w;
      pairs[lbase[b] + atomicAdd(&lcur[b], 1)] = v; }
  }
}

// ------- per-bucket CSR + deg + dinv + h1p = bf16(dinv * h1) epilogue -------
__global__ __launch_bounds__(512) void k_bcsr(const u32* __restrict__ pairs,
                                              const int* __restrict__ hist,
                                              int* __restrict__ colsrc,
                                              int* __restrict__ rowptr,
                                              int* __restrict__ deg,
                                              float* __restrict__ dinv,
                                              const float* __restrict__ h1,
                                              unsigned short* __restrict__ h1p) {
  __shared__ int hist256[256];
  __shared__ int scan[256];
  __shared__ int excl[256];
  __shared__ int cur[256];
  __shared__ float sdinv[256];
  int tid = threadIdx.x, b = blockIdx.x;
  if (tid < 256) { hist256[tid] = 0; cur[tid] = 0; }
  __syncthreads();
  int base = hist[b * GPART];
  int end  = (b == NB - 1) ? N_EDGES : hist[(b + 1) * GPART];
  int cnt  = end - base;
  for (int k = tid; k < cnt; k += 512)
    atomicAdd(&hist256[pairs[base + k] >> 17], 1);
  __syncthreads();
  if (tid < 256) scan[tid] = hist256[tid];
  __syncthreads();
  for (int off = 1; off < 256; off <<= 1) {
    int v = 0;
    if (tid < 256 && tid >= off) v = scan[tid - off];
    __syncthreads();
    if (tid < 256) scan[tid] += v;
    __syncthreads();
  }
  if (tid < 256) {
    int c = hist256[tid];
    int ex = scan[tid] - c;
    excl[tid] = ex;
    float dv = rsqrtf((float)(c + 1));
    sdinv[tid] = dv;
    int node = b * 256 + tid;
    if (node < N_NODES) {
      deg[node] = c;
      dinv[node] = dv;
      rowptr[node] = base + ex;
    }
  }
  __syncthreads();
  for (int k = tid; k < cnt; k += 512) {
    u32 v = pairs[base + k];
    int dl = v >> 17;
    colsrc[base + excl[dl] + atomicAdd(&cur[dl], 1)] = (int)(v & 0x1FFFF);
  }
  // epilogue: scale this bucket's h1 rows by dinv, store bf16
  int nmax = min(256, N_NODES - b * 256);
  for (int idx = tid; idx < nmax * 16; idx += 512) {
    int ln = idx >> 4, j = idx & 15;
    size_t n = (size_t)(b * 256 + ln);
    h1p[n * 16 + j] = f2bf(h1[n * 16 + j] * sdinv[ln]);
  }
}

// ============ fused agg1 (+bias+ReLU) + GEMM2 -> gfp bf16[N][8], dinv folded ====
// wave per node: c = lane&1 (bf16x8 half-row), q = lane>>1 (32 edge slots)
__global__ __launch_bounds__(256) void k_agg1g2(const unsigned short* __restrict__ h1p,
                                                const int* __restrict__ colsrc,
                                                const int* __restrict__ rowptr,
                                                const int* __restrict__ deg,
                                                const float* __restrict__ dinv,
                                                const float* __restrict__ b1,
                                                const float* __restrict__ W2,
                                                unsigned short* __restrict__ gfp) {
  __shared__ float hrow[4][16];
  int tid = threadIdx.x;
  int wv = tid >> 6, lane = tid & 63;
  int c = lane & 1, q = lane >> 1;
  int i = blockIdx.x * 4 + wv;                   // exact grid: 25000 blocks

  int jp = lane & 7;
  bool jv = jp < 7;
  float wcol[16];
#pragma unroll
  for (int k = 0; k < 16; k++) wcol[k] = jv ? W2[k * 7 + jp] : 0.f;

  int start = rowptr[i], cnt = deg[i];
  float acc[8];
#pragma unroll
  for (int k = 0; k < 8; k++) acc[k] = 0.f;

  const uint4* hp = (const uint4*)h1p;           // row i -> units i*2 + c
  for (int e = q; e < cnt; e += 32) {
    int src = colsrc[start + e];
    uint4 hv = hp[src * 2 + c];
    acc[0] += bflo(hv.x); acc[1] += bfhi(hv.x);
    acc[2] += bflo(hv.y); acc[3] += bfhi(hv.y);
    acc[4] += bflo(hv.z); acc[5] += bfhi(hv.z);
    acc[6] += bflo(hv.w); acc[7] += bfhi(hv.w);
  }
  if (q == 0) {                                  // self-loop term (dinv pre-folded)
    uint4 hv = hp[i * 2 + c];
    acc[0] += bflo(hv.x); acc[1] += bfhi(hv.x);
    acc[2] += bflo(hv.y); acc[3] += bfhi(hv.y);
    acc[4] += bflo(hv.z); acc[5] += bfhi(hv.z);
    acc[6] += bflo(hv.w); acc[7] += bfhi(hv.w);
  }
#pragma unroll
  for (int off = 2; off < 64; off <<= 1)
#pragma unroll
    for (int k = 0; k < 8; k++) acc[k] += __shfl_xor(acc[k], off, 64);

  float di = dinv[i];
  if (q == 0) {
#pragma unroll
    for (int k = 0; k < 8; k++)
      hrow[wv][c * 8 + k] = fmaxf(di * acc[k] + b1[c * 8 + k], 0.f);
  }
  __syncthreads();
  float o = 0.f;
#pragma unroll
  for (int k = 0; k < 16; k++) o += hrow[wv][k] * wcol[k];
  if (lane < 8) gfp[(size_t)i * 8 + jp] = jv ? f2bf(di * o) : (unsigned short)0;
}

// ============ agg2 + bias + log_softmax -> out [N,7] ============
// wave per node: c = lane&1 (bf16x4 half-row), q = lane>>1 (32 slots)
__global__ __launch_bounds__(256) void k_agg2(const unsigned short* __restrict__ gfp,
                                              const int* __restrict__ colsrc,
                                              const int* __restrict__ rowptr,
                                              const int* __restrict__ deg,
                                              const float* __restrict__ dinv,
                                              const float* __restrict__ b2,
                                              float* __restrict__ out) {
  int tid = threadIdx.x;
  int wv = tid >> 6, lane = tid & 63;
  int c = lane & 1, q = lane >> 1;
  int i = blockIdx.x * 4 + wv;                   // exact grid

  int start = rowptr[i], cnt = deg[i];
  float acc[4] = {0.f, 0.f, 0.f, 0.f};
  const uint2* gp = (const uint2*)gfp;           // row i -> units i*2 + c
  for (int e = q; e < cnt; e += 32) {
    int src = colsrc[start + e];
    uint2 gv = gp[src * 2 + c];
    acc[0] += bflo(gv.x); acc[1] += bfhi(gv.x);
    acc[2] += bflo(gv.y); acc[3] += bfhi(gv.y);
  }
  if (q == 0) {                                  // self-loop
    uint2 gv = gp[i * 2 + c];
    acc[0] += bflo(gv.x); acc[1] += bfhi(gv.x);
    acc[2] += bflo(gv.y); acc[3] += bfhi(gv.y);
  }
#pragma unroll
  for (int off = 2; off < 64; off <<= 1)
#pragma unroll
    for (int k = 0; k < 4; k++) acc[k] += __shfl_xor(acc[k], off, 64);

  float di = dinv[i];
  float v[4];
#pragma unroll
  for (int k = 0; k < 4; k++) {
    int f = c * 4 + k;
    v[k] = (f < 7) ? (di * acc[k] + b2[f]) : -1e30f;
  }
  float m = fmaxf(fmaxf(v[0], v[1]), fmaxf(v[2], v[3]));
  m = fmaxf(m, __shfl_xor(m, 1, 64));
  float s = __expf(v[0] - m) + __expf(v[1] - m) + __expf(v[2] - m) + __expf(v[3] - m);
  s += __shfl_xor(s, 1, 64);
  float ls = logf(s);
  if (q == 0) {
#pragma unroll
    for (int k = 0; k < 4; k++) {
      int f = c * 4 + k;
      if (f < 7) out[(size_t)i * 7 + f] = v[k] - m - ls;
    }
  }
}

extern "C" void kernel_launch(void* const* d_in, const int* in_sizes, int n_in,
                              void* d_out, int out_size, void* d_ws, size_t ws_size,
                              hipStream_t stream) {
  const float* x  = (const float*)d_in[0];
  const int*   ei = (const int*)d_in[1];     // [0..E)=src, [E..2E)=dst (int32)
  const float* W1 = (const float*)d_in[2];
  const float* b1 = (const float*)d_in[3];
  const float* W2 = (const float*)d_in[4];
  const float* b2 = (const float*)d_in[5];
  float* out = (float*)d_out;

  // workspace layout (~39 MB; d_ws ~800 MB)
  char* base = (char*)d_ws;
  int*   hist   = (int*)(base + 0);            //    800,768  (NBG*4)
  int*   bsums  = (int*)(base + 800768);       //      4,096
  int*   rowptr = (int*)(base + 804864);       //    400,128
  int*   deg    = (int*)(base + 1204992);      //    400,128
  float* dinv   = (float*)(base + 1605120);    //    400,128
  int*   colsrc = (int*)(base + 2005248);      // 12.8 MB  (ends 14,805,248)
  u32*   pairs  = (u32*)(base + 14805248);     // 12.8 MB  (ends 27,605,248)
  float* h1     = (float*)(base + 27605248);   //  6.4 MB  (ends 34,005,248)
  unsigned short* h1p = (unsigned short*)(base + 34005248); // 3.2 MB (ends 37,205,248)
  unsigned short* gfp = (unsigned short*)(base + 37205248); // 1.6 MB (ends 38,805,248)

  k_hist_gemm1<<<GPART + GEMM_BLKS, 256, 0, stream>>>(ei + N_EDGES, hist, x, W1, h1);
  k_scanA     <<<SCANA_G, 256, 0, stream>>>(hist, bsums);
  k_scanB     <<<1, 1024, 0, stream>>>(bsums);
  k_scanC     <<<SCANA_G, 256, 0, stream>>>(hist, bsums);
  k_part      <<<GPART, 256, 0, stream>>>(ei, ei + N_EDGES, hist, pairs);
  k_bcsr      <<<NB, 512, 0, stream>>>(pairs, hist, colsrc, rowptr, deg, dinv, h1, h1p);
  k_agg1g2    <<<N_NODES / 4, 256, 0, stream>>>(h1p, colsrc, rowptr, deg, dinv, b1, W2, gfp);
  k_agg2      <<<N_NODES / 4, 256, 0, stream>>>(gfp, colsrc, rowptr, deg, dinv, b2, out);
}